// Round 16
// baseline (2369.732 us; speedup 1.0000x reference)
//
#include <hip/hip_runtime.h>
#include <hip/hip_bf16.h>

typedef unsigned short u16;
typedef unsigned int u32;
typedef __attribute__((ext_vector_type(8))) short bf16x8;
typedef __attribute__((ext_vector_type(4))) float f32x4;

#define NG 100000
#define NV 200000
#define NE 500000
#define HD 128
#define NALL (NG + NV)          // combined node count: gene rows 0.., var rows NG..
#define EALL (2 * NE)

__device__ __forceinline__ float bflo(u32 w) { return __uint_as_float(w << 16); }
__device__ __forceinline__ float bfhi(u32 w) { return __uint_as_float(w & 0xffff0000u); }
__device__ __forceinline__ u16 f2bf(float f) {
    __hip_bfloat16 h = __float2bfloat16(f);
    u16 u; __builtin_memcpy(&u, &h, 2); return u;
}
__device__ __forceinline__ u32 pk2(float a, float b) {
    return (u32)f2bf(a) | ((u32)f2bf(b) << 16);
}

// ---- convert both f32 tables into one combined bf16 table [gene; var] ----
__global__ __launch_bounds__(256) void cvt_kernel(const float* __restrict__ g,
                                                  const float* __restrict__ v,
                                                  u16* __restrict__ out) {
    size_t slot = (size_t)blockIdx.x * 256 + threadIdx.x;   // 8 elems per slot
    size_t off = slot * 8;
    if (off >= (size_t)NALL * HD) return;
    const float* p = (off < (size_t)NG * HD) ? (g + off) : (v + (off - (size_t)NG * HD));
    float4 a = *(const float4*)p;
    float4 b = *(const float4*)(p + 4);
    uint4 pk;
    pk.x = pk2(a.x, a.y); pk.y = pk2(a.z, a.w);
    pk.z = pk2(b.x, b.y); pk.w = pk2(b.z, b.w);
    *(uint4*)(out + off) = pk;
}

// ---- convert 9 weight matrices f32 [128][128] -> fragment-ordered bf16 ----
__global__ __launch_bounds__(256) void wcvt_kernel(
    const float* w0, const float* w1, const float* w2, const float* w3,
    const float* w4, const float* w5, const float* w6, const float* w7,
    const float* w8, u16* __restrict__ out)
{
    const float* Ws[9] = {w0, w1, w2, w3, w4, w5, w6, w7, w8};
    const float* W = Ws[blockIdx.x];
    u16* o = out + (size_t)blockIdx.x * 16384;
    int tid = threadIdx.x;
#pragma unroll
    for (int it = 0; it < 8; ++it) {
        int slot = it * 256 + tid;       // 0..2047
        int f = slot >> 6, l = slot & 63;
        int kt = f >> 3, ct = f & 7;
        int row = ct * 16 + (l & 15);
        int kof = kt * 32 + (l >> 4) * 8;
        const float* wp = W + (size_t)row * HD + kof;
        float4 x = *(const float4*)wp;
        float4 y = *(const float4*)(wp + 4);
        uint4 pk;
        pk.x = pk2(x.x, x.y); pk.y = pk2(x.z, x.w);
        pk.z = pk2(y.x, y.y); pk.w = pk2(y.z, y.w);
        *(uint4*)(o + (size_t)slot * 8) = pk;
    }
}

// ---- combined histogram over both edge lists: dst var -> [0,NV), gene -> NV+ ----
__global__ __launch_bounds__(256) void hist2_kernel(const int* __restrict__ dst_gv,
                                                    const int* __restrict__ dst_vg,
                                                    int* __restrict__ deg) {
    int t = blockIdx.x * 256 + threadIdx.x;
    if (t < NE)            atomicAdd(&deg[dst_gv[t]], 1);
    else if (t < EALL)     atomicAdd(&deg[NV + dst_vg[t - NE]], 1);
}

// ---- scan stage 1: per-block (2048) exclusive scan + block sums ----
__global__ __launch_bounds__(256) void scan1_kernel(const int* __restrict__ deg,
                                                    int* __restrict__ excl,
                                                    int* __restrict__ bsum, int N) {
    __shared__ int lds[256];
    int tid = threadIdx.x;
    int base = blockIdx.x * 2048 + tid * 8;
    int v[8]; int s = 0;
#pragma unroll
    for (int i = 0; i < 8; ++i) { v[i] = (base + i < N) ? deg[base + i] : 0; s += v[i]; }
    lds[tid] = s;
    __syncthreads();
    for (int off = 1; off < 256; off <<= 1) {
        int x = (tid >= off) ? lds[tid - off] : 0;
        __syncthreads();
        lds[tid] += x;
        __syncthreads();
    }
    int run = lds[tid] - s;
#pragma unroll
    for (int i = 0; i < 8; ++i) {
        if (base + i < N) excl[base + i] = run;
        run += v[i];
    }
    if (tid == 255) bsum[blockIdx.x] = lds[255];
}

__global__ void scan2_kernel(int* __restrict__ bsum, int nb) {
    if (threadIdx.x == 0 && blockIdx.x == 0) {
        int run = 0;
        for (int i = 0; i < nb; ++i) { int t = bsum[i]; bsum[i] = run; run += t; }
    }
}

__global__ __launch_bounds__(256) void scan3_kernel(int* __restrict__ rs,
                                                    int* __restrict__ cur,
                                                    const int* __restrict__ bsum, int N) {
    int i = blockIdx.x * 256 + threadIdx.x;
    if (i < N) {
        int v = rs[i] + bsum[i >> 11];
        rs[i] = v;
        cur[i] = v;
    }
    if (i == 0) rs[N] = EALL;
}

// ---- combined edge scatter; esrc stored pre-offset into the combined table ----
__global__ __launch_bounds__(256) void escatter2_kernel(const int* __restrict__ src_gv,
                                                        const int* __restrict__ dst_gv,
                                                        const int* __restrict__ src_vg,
                                                        const int* __restrict__ dst_vg,
                                                        int* __restrict__ cur,
                                                        int* __restrict__ esrc) {
    int t = blockIdx.x * 256 + threadIdx.x;
    if (t < NE) {
        int p = atomicAdd(&cur[dst_gv[t]], 1);
        esrc[p] = src_gv[t];
    } else if (t < EALL) {
        int e = t - NE;
        int p = atomicAdd(&cur[NV + dst_vg[e]], 1);
        esrc[p] = NG + src_vg[e];
    }
}

// ---- degree-sort (counting sort, 64 bins, per segment) -> perm ----
// perm[slot] holds the LOCAL row id; var slots 0..NV-1, gene slots NV.. .
// Output values are slot-permutation-invariant, so cursor race order is fine.
__global__ __launch_bounds__(256) void dhist_kernel(const int* __restrict__ rs,
                                                    int* __restrict__ dh) {
    int i = blockIdx.x * 256 + threadIdx.x;
    if (i < NALL) {
        int d = rs[i + 1] - rs[i]; if (d > 63) d = 63;
        int seg = (i < NV) ? 0 : 1;
        atomicAdd(&dh[seg * 64 + d], 1);
    }
}
__global__ void dscan_kernel(int* __restrict__ dh, int* __restrict__ dcur) {
    if (threadIdx.x == 0 && blockIdx.x == 0) {
        for (int s = 0; s < 2; ++s) {
            int run = 0;
            for (int b = 0; b < 64; ++b) {
                int t = dh[s * 64 + b];
                dh[s * 64 + b] = run; dcur[s * 64 + b] = run;
                run += t;
            }
        }
    }
}
__global__ __launch_bounds__(256) void dscatter_kernel(const int* __restrict__ rs,
                                                       int* __restrict__ dcur,
                                                       int* __restrict__ perm) {
    int i = blockIdx.x * 256 + threadIdx.x;
    if (i < NALL) {
        int d = rs[i + 1] - rs[i]; if (d > 63) d = 63;
        int seg = (i < NV) ? 0 : 1;
        int pos = atomicAdd(&dcur[seg * 64 + d], 1);
        perm[(seg ? NV : 0) + pos] = seg ? (i - NV) : i;
    }
}

// ---- fused aggregate + dual-segment MFMA SAGE linear, 64-row blocks ----
// Round-16: DEGREE-SORTED slot order. Gather-wave trip count was
// max(ceil(deg/4)) over the wave's 4 rows (G5 divergence, ~1.5-2x tax with
// Poisson degrees); sorted slots make trips uniform and blocks load-balanced.
// perm applied at CSR lookup, phase-1 self-row load, and epilogue store
// (256 B chunks, full sectors). Per-row arithmetic bit-identical.
// Single-row gather (~80 regs true demand), __launch_bounds__(256,6) (cap 85,
// no spill). LDS 17408 B. Swizzle: chunk (row,c) at row*256B + ((c^(row&15)))*16B.
// Fragment map (m89-verified): A row=lane&15, k=8*(lane>>4)+j; B col=lane&15;
// D col=lane&15, row=4*(lane>>4)+reg.
template <int RELU, int OBF16>
__global__ __launch_bounds__(256, 6) void fused_sage_kernel(
    const u16* __restrict__ Xb,     // combined [gene; var] bf16 table
    const int* __restrict__ rs,     // CSR row starts (var 0.., gene NV..)
    const int* __restrict__ esrc,   // edge sources (combined X row index)
    const int* __restrict__ perm,   // degree-sorted slot -> local row
    const u16* __restrict__ wf_v, const u16* __restrict__ wf_g,
    const float* __restrict__ b_v, const float* __restrict__ b_g,
    float* __restrict__ outf_v, float* __restrict__ outf_g,
    u16* __restrict__ outb_v, u16* __restrict__ outb_g,
    int nvb)
{
    __shared__ __align__(16) char ldsbuf[17408];   // atile 16384 | epilogue 17408 (union)
    u16* atile = (u16*)ldsbuf;                     // [64][128] swizzled

    const bool isVar = (int)blockIdx.x < nvb;
    const int bseg = isVar ? blockIdx.x : blockIdx.x - nvb;
    const int Nseg = isVar ? NV : NG;
    const int gseg = isVar ? 0 : NV;                      // CSR row-space offset
    const int pbase = isVar ? 0 : NV;                     // perm slot base
    const u16* Xseg = Xb + (size_t)(isVar ? NG : 0) * HD; // self rows
    const u16* wf = isVar ? wf_v : wf_g;
    const float* bias = isVar ? b_v : b_g;
    float* outf = isVar ? outf_v : outf_g;
    u16* outb = isVar ? outb_v : outb_g;

    const int tid = threadIdx.x;
    const int lane = tid & 63;
    const int wid = tid >> 6;
    const int m0 = bseg * 64 + wid * 16;
    const int lr = lane & 15, lg = lane >> 4;

    // ---- phase A: gather-mean 64 sorted-slot rows into swizzled LDS tile ----
    {
        const int c = tid & 15;
#pragma unroll 1
        for (int it = 0; it < 4; ++it) {
            int lrow = it * 16 + (tid >> 4);
            int slot = bseg * 64 + lrow;
            float s[8] = {0.f, 0.f, 0.f, 0.f, 0.f, 0.f, 0.f, 0.f};
            float rcv = 0.f;
            if (slot < Nseg) {
                int srow = perm[pbase + slot];
                int e0 = rs[gseg + srow], e1 = rs[gseg + srow + 1];
                if (e1 > e0) {
                    rcv = 1.f / (float)(e1 - e0);
                    for (int e = e0; e < e1; e += 4) {   // 4 loads in flight, predicated
                        uint4 d[4];
                        float m[4];
#pragma unroll
                        for (int i = 0; i < 4; ++i) {
                            int ee = e + i;
                            int idx = esrc[ee < e1 ? ee : e1 - 1];
                            m[i] = (ee < e1) ? 1.f : 0.f;
                            d[i] = *(const uint4*)(Xb + (size_t)idx * HD + c * 8);
                        }
#pragma unroll
                        for (int i = 0; i < 4; ++i) {
                            u32 w[4] = {d[i].x, d[i].y, d[i].z, d[i].w};
#pragma unroll
                            for (int j = 0; j < 4; ++j) {
                                s[2 * j]     = fmaf(m[i], bflo(w[j]), s[2 * j]);
                                s[2 * j + 1] = fmaf(m[i], bfhi(w[j]), s[2 * j + 1]);
                            }
                        }
                    }
                }
            }
            uint4 pk;
            pk.x = pk2(s[0] * rcv, s[1] * rcv);
            pk.y = pk2(s[2] * rcv, s[3] * rcv);
            pk.z = pk2(s[4] * rcv, s[5] * rcv);
            pk.w = pk2(s[6] * rcv, s[7] * rcv);
            *(uint4*)(atile + lrow * 128 + ((c ^ (lrow & 15)) << 3)) = pk;
        }
    }
    __syncthreads();

    // ---- phase B: dual-phase MFMA (wave's 16 slots) ----
    f32x4 acc[8];
#pragma unroll
    for (int ct = 0; ct < 8; ++ct) acc[ct] = (f32x4){0.f, 0.f, 0.f, 0.f};

    // phase 0: A = LDS agg tile (swizzled); lrow&15 == lr here
    {
        const u16* wp = wf;
        bf16x8 a[4];
#pragma unroll
        for (int kt = 0; kt < 4; ++kt) {
            int lrow = wid * 16 + lr;
            int ck = (kt * 4 + lg) ^ lr;
            a[kt] = *(const bf16x8*)(atile + lrow * 128 + (ck << 3));
        }
#pragma unroll
        for (int kt = 0; kt < 4; ++kt)
#pragma unroll
            for (int ct = 0; ct < 8; ++ct) {
                bf16x8 w = *(const bf16x8*)(wp + (size_t)(((kt * 8 + ct) << 6) + lane) * 8);
                acc[ct] = __builtin_amdgcn_mfma_f32_16x16x32_bf16(a[kt], w, acc[ct], 0, 0, 0);
            }
    }
    // phase 1: A = self rows (perm'd) from global
    {
        const u16* wp = wf + 16384;
        int slot = m0 + lr; if (slot > Nseg - 1) slot = Nseg - 1;
        int row = perm[pbase + slot];
        bf16x8 a[4];
#pragma unroll
        for (int kt = 0; kt < 4; ++kt)
            a[kt] = *(const bf16x8*)(Xseg + (size_t)row * HD + kt * 32 + lg * 8);
#pragma unroll
        for (int kt = 0; kt < 4; ++kt)
#pragma unroll
            for (int ct = 0; ct < 8; ++ct) {
                bf16x8 w = *(const bf16x8*)(wp + (size_t)(((kt * 8 + ct) << 6) + lane) * 8);
                acc[ct] = __builtin_amdgcn_mfma_f32_16x16x32_bf16(a[kt], w, acc[ct], 0, 0, 0);
            }
    }

    float bv[8];
#pragma unroll
    for (int ct = 0; ct < 8; ++ct) bv[ct] = bias[ct * 16 + lr];

    // ---- phase C: epilogue via per-wave LDS tiles; perm'd 256 B-chunk stores ----
    __syncthreads();
    if (OBF16) {
        u16 (*lds_u)[16][136] = (u16 (*)[16][136])ldsbuf;   // 17408 B total
#pragma unroll
        for (int ct = 0; ct < 8; ++ct)
#pragma unroll
            for (int r = 0; r < 4; ++r) {
                float v = acc[ct][r] + bv[ct];
                if (RELU) v = fmaxf(v, 0.f);
                lds_u[wid][lg * 4 + r][ct * 16 + lr] = f2bf(v);
            }
#pragma unroll
        for (int i = 0; i < 4; ++i) {
            int row16 = i * 4 + lg;
            int colb = lr * 8;
            uint4 pk = *(const uint4*)&lds_u[wid][row16][colb];
            int slot = m0 + row16;
            if (slot < Nseg) {
                int orow = perm[pbase + slot];
                *(uint4*)(outb + (size_t)orow * HD + colb) = pk;
            }
        }
    } else {
        float (*lds_f)[16][68] = (float (*)[16][68])ldsbuf;  // 17408 B total
#pragma unroll
        for (int p = 0; p < 2; ++p) {   // column halves
#pragma unroll
            for (int cq = 0; cq < 4; ++cq) {
                int ct = p * 4 + cq;
#pragma unroll
                for (int r = 0; r < 4; ++r) {
                    float v = acc[ct][r] + bv[ct];
                    if (RELU) v = fmaxf(v, 0.f);
                    lds_f[wid][lg * 4 + r][cq * 16 + lr] = v;
                }
            }
#pragma unroll
            for (int i = 0; i < 4; ++i) {
                int row16 = i * 4 + lg;
                int colb = lr * 4;
                f32x4 v = *(const f32x4*)&lds_f[wid][row16][colb];
                int slot = m0 + row16;
                if (slot < Nseg) {
                    int orow = perm[pbase + slot];
                    __builtin_nontemporal_store(v, (f32x4*)(outf + (size_t)orow * HD + p * 64 + colb));
                }
            }
        }
    }
}

// ---- fused adversarial head: adv = relu(g2 @ A1^T + b1) @ A2^T + b2 ----
__global__ __launch_bounds__(256, 4) void head_kernel(
    const float* __restrict__ g2,     // f32 [NG][128] (out_gene2)
    const u16* __restrict__ wfA1,     // A1 frag buf
    const float* __restrict__ b1,
    const float* __restrict__ A2,     // f32 [8][128]
    const float* __restrict__ b2,
    float* __restrict__ adv)          // f32 [NG][8]
{
    __shared__ __align__(16) u16 lds_h[4][16][136];
    const int tid = threadIdx.x;
    const int lane = tid & 63;
    const int wid = tid >> 6;
    const int m0 = blockIdx.x * 128 + wid * 32;
    const int lr = lane & 15, lg = lane >> 4;

    bf16x8 a2f[4];
#pragma unroll
    for (int kt = 0; kt < 4; ++kt) {
        union { u16 s[8]; bf16x8 v; } u;
        if (lr < 8) {
            const float* p = A2 + (size_t)lr * HD + kt * 32 + lg * 8;
            float4 x = *(const float4*)p;
            float4 y = *(const float4*)(p + 4);
            u.s[0] = f2bf(x.x); u.s[1] = f2bf(x.y); u.s[2] = f2bf(x.z); u.s[3] = f2bf(x.w);
            u.s[4] = f2bf(y.x); u.s[5] = f2bf(y.y); u.s[6] = f2bf(y.z); u.s[7] = f2bf(y.w);
        } else {
#pragma unroll
            for (int i = 0; i < 8; ++i) u.s[i] = 0;
        }
        a2f[kt] = u.v;
    }

    f32x4 acc[2][8];
#pragma unroll
    for (int rt = 0; rt < 2; ++rt)
#pragma unroll
        for (int ct = 0; ct < 8; ++ct) acc[rt][ct] = (f32x4){0.f, 0.f, 0.f, 0.f};

#pragma unroll
    for (int kt = 0; kt < 4; ++kt) {
        bf16x8 a[2];
#pragma unroll
        for (int rt = 0; rt < 2; ++rt) {
            int row = m0 + rt * 16 + lr; if (row > NG - 1) row = NG - 1;
            const float* p = g2 + (size_t)row * HD + kt * 32 + lg * 8;
            float4 x = *(const float4*)p;
            float4 y = *(const float4*)(p + 4);
            union { u16 s[8]; bf16x8 v; } u;
            u.s[0] = f2bf(x.x); u.s[1] = f2bf(x.y); u.s[2] = f2bf(x.z); u.s[3] = f2bf(x.w);
            u.s[4] = f2bf(y.x); u.s[5] = f2bf(y.y); u.s[6] = f2bf(y.z); u.s[7] = f2bf(y.w);
            a[rt] = u.v;
        }
#pragma unroll
        for (int ct = 0; ct < 8; ++ct) {
            bf16x8 w = *(const bf16x8*)(wfA1 + (size_t)(((kt * 8 + ct) << 6) + lane) * 8);
#pragma unroll
            for (int rt = 0; rt < 2; ++rt)
                acc[rt][ct] = __builtin_amdgcn_mfma_f32_16x16x32_bf16(
                    a[rt], w, acc[rt][ct], 0, 0, 0);
        }
    }

    float b1v[8];
#pragma unroll
    for (int ct = 0; ct < 8; ++ct) b1v[ct] = b1[ct * 16 + lr];
    float b2v = (lr < 8) ? b2[lr] : 0.f;

#pragma unroll
    for (int rt = 0; rt < 2; ++rt) {
#pragma unroll
        for (int ct = 0; ct < 8; ++ct)
#pragma unroll
            for (int r = 0; r < 4; ++r) {
                float v = fmaxf(acc[rt][ct][r] + b1v[ct], 0.f);
                lds_h[wid][lg * 4 + r][ct * 16 + lr] = f2bf(v);
            }
        f32x4 av = (f32x4){0.f, 0.f, 0.f, 0.f};
#pragma unroll
        for (int kt = 0; kt < 4; ++kt) {
            bf16x8 h = *(const bf16x8*)&lds_h[wid][lr][kt * 32 + lg * 8];
            av = __builtin_amdgcn_mfma_f32_16x16x32_bf16(h, a2f[kt], av, 0, 0, 0);
        }
        if (lr < 8) {
#pragma unroll
            for (int r = 0; r < 4; ++r) {
                int grow = m0 + rt * 16 + lg * 4 + r;
                if (grow < NG)
                    __builtin_nontemporal_store(av[r] + b2v, &adv[(size_t)grow * 8 + lr]);
            }
        }
    }
}

extern "C" void kernel_launch(void* const* d_in, const int* in_sizes, int n_in,
                              void* d_out, int out_size, void* d_ws, size_t ws_size,
                              hipStream_t stream)
{
    const float* emb_gene = (const float*)d_in[0];
    const float* emb_var  = (const float*)d_in[1];
    const float* Wl1_gv = (const float*)d_in[2];
    const float* bl1_gv = (const float*)d_in[3];
    const float* Wr1_gv = (const float*)d_in[4];
    const float* Wl1_vg = (const float*)d_in[5];
    const float* bl1_vg = (const float*)d_in[6];
    const float* Wr1_vg = (const float*)d_in[7];
    const float* Wl2_gv = (const float*)d_in[8];
    const float* bl2_gv = (const float*)d_in[9];
    const float* Wr2_gv = (const float*)d_in[10];
    const float* Wl2_vg = (const float*)d_in[11];
    const float* bl2_vg = (const float*)d_in[12];
    const float* Wr2_vg = (const float*)d_in[13];
    const float* A1 = (const float*)d_in[14];
    const float* b1 = (const float*)d_in[15];
    const float* A2 = (const float*)d_in[16];
    const float* b2 = (const float*)d_in[17];
    const int* src_gv = (const int*)d_in[18];
    const int* dst_gv = (const int*)d_in[19];
    const int* src_vg = (const int*)d_in[20];
    const int* dst_vg = (const int*)d_in[21];

    // ws layout (bytes) — ws_size ≈ 627 MB (measured r5 poison fill):
    char* ws = (char*)d_ws;
    u16* embb  = (u16*)(ws);                  // bf16 [NALL][128] gene;var  76.8 MB
    u16* zb    = (u16*)(ws + 76800000);       // bf16 [NALL][128] gene;var  76.8 MB
    u16* wfrag = (u16*)(ws + 153600000);      // 9 x 32 KB fragment bufs
    int* rs    = (int*)(ws + 154000000);      // [NALL+1]
    int* esrc  = (int*)(ws + 155300000);      // [2E]
    int* deg   = (int*)(ws + 159300000);      // [NALL] transient
    int* cur   = (int*)(ws + 160500000);      // [NALL] transient
    int* bsum  = (int*)(ws + 161700000);      // [147]
    int* perm  = (int*)(ws + 161800000);      // [NALL] degree-sorted slots
    int* dh    = (int*)(ws + 163100000);      // [128] degree bins
    int* dcur  = (int*)(ws + 163200000);      // [128] cursors

    float* out       = (float*)d_out;
    float* out_gene2 = out;                          // [NG][128]
    float* out_var2  = out + (size_t)NG * HD;        // [NV][128]
    float* out_adv   = out + (size_t)(NG + NV) * HD; // [NG][8]

    const int NB = (NALL + 2047) / 2048;   // 147
    const int EB2 = (EALL + 255) / 256;    // 3907
    const int NAB = (NALL + 255) / 256;    // 1172
    const int NVB = (NV + 63) / 64;        // 3125
    const int NGB = (NG + 63) / 64;        // 1563
    const int NGB128 = (NG + 127) / 128;   // 782 (head)
    const int CVB = (int)(((size_t)NALL * HD / 8 + 255) / 256);  // 18750

    // ---- prep: bf16 tables + W fragment bufs + CSR + degree-sort ----
    hipMemsetAsync(deg, 0, (size_t)NALL * 4, stream);
    hipMemsetAsync(dh, 0, 512, stream);
    cvt_kernel<<<CVB, 256, 0, stream>>>(emb_gene, emb_var, embb);
    wcvt_kernel<<<9, 256, 0, stream>>>(Wl1_gv, Wr1_gv, Wl1_vg, Wr1_vg,
                                       Wl2_gv, Wr2_gv, Wl2_vg, Wr2_vg, A1, wfrag);
    hist2_kernel<<<EB2, 256, 0, stream>>>(dst_gv, dst_vg, deg);
    scan1_kernel<<<NB, 256, 0, stream>>>(deg, rs, bsum, NALL);
    scan2_kernel<<<1, 64, 0, stream>>>(bsum, NB);
    scan3_kernel<<<NAB, 256, 0, stream>>>(rs, cur, bsum, NALL);
    escatter2_kernel<<<EB2, 256, 0, stream>>>(src_gv, dst_gv, src_vg, dst_vg, cur, esrc);
    dhist_kernel<<<NAB, 256, 0, stream>>>(rs, dh);
    dscan_kernel<<<1, 64, 0, stream>>>(dh, dcur);
    dscatter_kernel<<<NAB, 256, 0, stream>>>(rs, dcur, perm);

    // ---- layer 1: fused gather-mean + MFMA dual-GEMM -> zb (bf16, relu) ----
    fused_sage_kernel<1, 1><<<NVB + NGB, 256, 0, stream>>>(embb, rs, esrc, perm,
        wfrag + 0 * 16384, wfrag + 2 * 16384, bl1_gv, bl1_vg,
        nullptr, nullptr,
        zb + (size_t)NG * HD, zb,
        NVB);

    // ---- layer 2: fused gather-mean + MFMA dual-GEMM -> d_out (f32, NT stores) ----
    fused_sage_kernel<0, 0><<<NVB + NGB, 256, 0, stream>>>(zb, rs, esrc, perm,
        wfrag + 4 * 16384, wfrag + 6 * 16384, bl2_gv, bl2_vg,
        out_var2, out_gene2,
        nullptr, nullptr,
        NVB);

    // ---- fused adversarial head ----
    head_kernel<<<NGB128, 256, 0, stream>>>(out_gene2, wfrag + 8 * 16384, b1, A2, b2, out_adv);
}

// Round 17
// 494.981 us; speedup vs baseline: 4.7875x; 4.7875x over previous
//
#include <hip/hip_runtime.h>
#include <hip/hip_bf16.h>

typedef unsigned short u16;
typedef unsigned int u32;
typedef __attribute__((ext_vector_type(8))) short bf16x8;
typedef __attribute__((ext_vector_type(4))) float f32x4;

#define NG 100000
#define NV 200000
#define NE 500000
#define HD 128
#define NALL (NG + NV)          // combined node count: gene rows 0.., var rows NG..
#define EALL (2 * NE)
#define NSB 256                 // sort blocks
#define CHUNK ((NALL + NSB - 1) / NSB)   // 1172

__device__ __forceinline__ float bflo(u32 w) { return __uint_as_float(w << 16); }
__device__ __forceinline__ float bfhi(u32 w) { return __uint_as_float(w & 0xffff0000u); }
__device__ __forceinline__ u16 f2bf(float f) {
    __hip_bfloat16 h = __float2bfloat16(f);
    u16 u; __builtin_memcpy(&u, &h, 2); return u;
}
__device__ __forceinline__ u32 pk2(float a, float b) {
    return (u32)f2bf(a) | ((u32)f2bf(b) << 16);
}

// ---- convert both f32 tables into one combined bf16 table [gene; var] ----
__global__ __launch_bounds__(256) void cvt_kernel(const float* __restrict__ g,
                                                  const float* __restrict__ v,
                                                  u16* __restrict__ out) {
    size_t slot = (size_t)blockIdx.x * 256 + threadIdx.x;   // 8 elems per slot
    size_t off = slot * 8;
    if (off >= (size_t)NALL * HD) return;
    const float* p = (off < (size_t)NG * HD) ? (g + off) : (v + (off - (size_t)NG * HD));
    float4 a = *(const float4*)p;
    float4 b = *(const float4*)(p + 4);
    uint4 pk;
    pk.x = pk2(a.x, a.y); pk.y = pk2(a.z, a.w);
    pk.z = pk2(b.x, b.y); pk.w = pk2(b.z, b.w);
    *(uint4*)(out + off) = pk;
}

// ---- convert 9 weight matrices f32 [128][128] -> fragment-ordered bf16 ----
__global__ __launch_bounds__(256) void wcvt_kernel(
    const float* w0, const float* w1, const float* w2, const float* w3,
    const float* w4, const float* w5, const float* w6, const float* w7,
    const float* w8, u16* __restrict__ out)
{
    const float* Ws[9] = {w0, w1, w2, w3, w4, w5, w6, w7, w8};
    const float* W = Ws[blockIdx.x];
    u16* o = out + (size_t)blockIdx.x * 16384;
    int tid = threadIdx.x;
#pragma unroll
    for (int it = 0; it < 8; ++it) {
        int slot = it * 256 + tid;       // 0..2047
        int f = slot >> 6, l = slot & 63;
        int kt = f >> 3, ct = f & 7;
        int row = ct * 16 + (l & 15);
        int kof = kt * 32 + (l >> 4) * 8;
        const float* wp = W + (size_t)row * HD + kof;
        float4 x = *(const float4*)wp;
        float4 y = *(const float4*)(wp + 4);
        uint4 pk;
        pk.x = pk2(x.x, x.y); pk.y = pk2(x.z, x.w);
        pk.z = pk2(y.x, y.y); pk.w = pk2(y.z, y.w);
        *(uint4*)(o + (size_t)slot * 8) = pk;
    }
}

// ---- combined histogram over both edge lists: dst var -> [0,NV), gene -> NV+ ----
__global__ __launch_bounds__(256) void hist2_kernel(const int* __restrict__ dst_gv,
                                                    const int* __restrict__ dst_vg,
                                                    int* __restrict__ deg) {
    int t = blockIdx.x * 256 + threadIdx.x;
    if (t < NE)            atomicAdd(&deg[dst_gv[t]], 1);
    else if (t < EALL)     atomicAdd(&deg[NV + dst_vg[t - NE]], 1);
}

// ---- scan stage 1: per-block (2048) exclusive scan + block sums ----
__global__ __launch_bounds__(256) void scan1_kernel(const int* __restrict__ deg,
                                                    int* __restrict__ excl,
                                                    int* __restrict__ bsum, int N) {
    __shared__ int lds[256];
    int tid = threadIdx.x;
    int base = blockIdx.x * 2048 + tid * 8;
    int v[8]; int s = 0;
#pragma unroll
    for (int i = 0; i < 8; ++i) { v[i] = (base + i < N) ? deg[base + i] : 0; s += v[i]; }
    lds[tid] = s;
    __syncthreads();
    for (int off = 1; off < 256; off <<= 1) {
        int x = (tid >= off) ? lds[tid - off] : 0;
        __syncthreads();
        lds[tid] += x;
        __syncthreads();
    }
    int run = lds[tid] - s;
#pragma unroll
    for (int i = 0; i < 8; ++i) {
        if (base + i < N) excl[base + i] = run;
        run += v[i];
    }
    if (tid == 255) bsum[blockIdx.x] = lds[255];
}

__global__ void scan2_kernel(int* __restrict__ bsum, int nb) {
    if (threadIdx.x == 0 && blockIdx.x == 0) {
        int run = 0;
        for (int i = 0; i < nb; ++i) { int t = bsum[i]; bsum[i] = run; run += t; }
    }
}

__global__ __launch_bounds__(256) void scan3_kernel(int* __restrict__ rs,
                                                    int* __restrict__ cur,
                                                    const int* __restrict__ bsum, int N) {
    int i = blockIdx.x * 256 + threadIdx.x;
    if (i < N) {
        int v = rs[i] + bsum[i >> 11];
        rs[i] = v;
        cur[i] = v;
    }
    if (i == 0) rs[N] = EALL;
}

// ---- combined edge scatter; esrc stored pre-offset into the combined table ----
__global__ __launch_bounds__(256) void escatter2_kernel(const int* __restrict__ src_gv,
                                                        const int* __restrict__ dst_gv,
                                                        const int* __restrict__ src_vg,
                                                        const int* __restrict__ dst_vg,
                                                        int* __restrict__ cur,
                                                        int* __restrict__ esrc) {
    int t = blockIdx.x * 256 + threadIdx.x;
    if (t < NE) {
        int p = atomicAdd(&cur[dst_gv[t]], 1);
        esrc[p] = src_gv[t];
    } else if (t < EALL) {
        int e = t - NE;
        int p = atomicAdd(&cur[NV + dst_vg[e]], 1);
        esrc[p] = NG + src_vg[e];
    }
}

// ---- degree-sort, contention-free (r16 lesson: 300K global atomics on 128
// addresses = ~1 ms/kernel; G12: aggregate locally first) ----
// sortA: per-block LDS histogram of its row chunk -> bcounts[block][128]
__global__ __launch_bounds__(256) void sortA_kernel(const int* __restrict__ rs,
                                                    int* __restrict__ bcounts) {
    __shared__ int h[128];
    int tid = threadIdx.x;
    if (tid < 128) h[tid] = 0;
    __syncthreads();
    int b = blockIdx.x;
    int start = b * CHUNK, end = min(start + CHUNK, NALL);
    for (int i = start + tid; i < end; i += 256) {
        int d = rs[i + 1] - rs[i]; if (d > 63) d = 63;
        int seg = (i < NV) ? 0 : 1;
        atomicAdd(&h[seg * 64 + d], 1);
    }
    __syncthreads();
    if (tid < 128) bcounts[b * 128 + tid] = h[tid];
}
// sortB: one block, 128 threads (one bin each): per-bin exclusive prefix over
// blocks + per-segment bin-base prefix. Loads independent -> unroll pipelines.
__global__ void sortB_kernel(const int* __restrict__ bcounts, int* __restrict__ boffs) {
    __shared__ int btot[128];
    __shared__ int bbase[128];
    int bin = threadIdx.x;   // 128 threads
    int run = 0;
#pragma unroll 8
    for (int b = 0; b < NSB; ++b) {
        boffs[b * 128 + bin] = run;
        run += bcounts[b * 128 + bin];
    }
    btot[bin] = run;
    __syncthreads();
    if (bin == 0) {
        int r0 = 0;
        for (int d = 0; d < 64; ++d) { bbase[d] = r0; r0 += btot[d]; }
        int r1 = 0;
        for (int d = 0; d < 64; ++d) { bbase[64 + d] = r1; r1 += btot[64 + d]; }
    }
    __syncthreads();
    int base = bbase[bin];
#pragma unroll 8
    for (int b = 0; b < NSB; ++b) boffs[b * 128 + bin] += base;
}
// sortC: re-walk chunk; LDS cursors seeded from boffs; emit perm.
// perm[slot]: var slots [0,NV) hold local var row; gene slots [NV,NALL) local gene row.
__global__ __launch_bounds__(256) void sortC_kernel(const int* __restrict__ rs,
                                                    const int* __restrict__ boffs,
                                                    int* __restrict__ perm) {
    __shared__ int curh[128];
    int tid = threadIdx.x;
    int b = blockIdx.x;
    if (tid < 128) curh[tid] = boffs[b * 128 + tid];
    __syncthreads();
    int start = b * CHUNK, end = min(start + CHUNK, NALL);
    for (int i = start + tid; i < end; i += 256) {
        int d = rs[i + 1] - rs[i]; if (d > 63) d = 63;
        int seg = (i < NV) ? 0 : 1;
        int pos = atomicAdd(&curh[seg * 64 + d], 1);
        perm[(seg ? NV : 0) + pos] = seg ? (i - NV) : i;
    }
}

// ---- fused aggregate + dual-segment MFMA SAGE linear, 64-row blocks ----
// Degree-sorted slot order (uniform gather trip counts per wave; blocks
// load-balanced). perm applied at CSR lookup, phase-1 self-row load, epilogue
// store (256 B chunks). Per-row arithmetic bit-identical to unsorted.
// Single-row gather (~80 regs true demand), __launch_bounds__(256,6) (cap 85,
// no spill). LDS 17408 B. Swizzle: chunk (row,c) at row*256B + ((c^(row&15)))*16B.
// Fragment map (m89-verified): A row=lane&15, k=8*(lane>>4)+j; B col=lane&15;
// D col=lane&15, row=4*(lane>>4)+reg.
template <int RELU, int OBF16>
__global__ __launch_bounds__(256, 6) void fused_sage_kernel(
    const u16* __restrict__ Xb,     // combined [gene; var] bf16 table
    const int* __restrict__ rs,     // CSR row starts (var 0.., gene NV..)
    const int* __restrict__ esrc,   // edge sources (combined X row index)
    const int* __restrict__ perm,   // degree-sorted slot -> local row
    const u16* __restrict__ wf_v, const u16* __restrict__ wf_g,
    const float* __restrict__ b_v, const float* __restrict__ b_g,
    float* __restrict__ outf_v, float* __restrict__ outf_g,
    u16* __restrict__ outb_v, u16* __restrict__ outb_g,
    int nvb)
{
    __shared__ __align__(16) char ldsbuf[17408];   // atile 16384 | epilogue 17408 (union)
    u16* atile = (u16*)ldsbuf;                     // [64][128] swizzled

    const bool isVar = (int)blockIdx.x < nvb;
    const int bseg = isVar ? blockIdx.x : blockIdx.x - nvb;
    const int Nseg = isVar ? NV : NG;
    const int gseg = isVar ? 0 : NV;                      // CSR row-space offset
    const int pbase = isVar ? 0 : NV;                     // perm slot base
    const u16* Xseg = Xb + (size_t)(isVar ? NG : 0) * HD; // self rows
    const u16* wf = isVar ? wf_v : wf_g;
    const float* bias = isVar ? b_v : b_g;
    float* outf = isVar ? outf_v : outf_g;
    u16* outb = isVar ? outb_v : outb_g;

    const int tid = threadIdx.x;
    const int lane = tid & 63;
    const int wid = tid >> 6;
    const int m0 = bseg * 64 + wid * 16;
    const int lr = lane & 15, lg = lane >> 4;

    // ---- phase A: gather-mean 64 sorted-slot rows into swizzled LDS tile ----
    {
        const int c = tid & 15;
#pragma unroll 1
        for (int it = 0; it < 4; ++it) {
            int lrow = it * 16 + (tid >> 4);
            int slot = bseg * 64 + lrow;
            float s[8] = {0.f, 0.f, 0.f, 0.f, 0.f, 0.f, 0.f, 0.f};
            float rcv = 0.f;
            if (slot < Nseg) {
                int srow = perm[pbase + slot];
                int e0 = rs[gseg + srow], e1 = rs[gseg + srow + 1];
                if (e1 > e0) {
                    rcv = 1.f / (float)(e1 - e0);
                    for (int e = e0; e < e1; e += 4) {   // 4 loads in flight, predicated
                        uint4 d[4];
                        float m[4];
#pragma unroll
                        for (int i = 0; i < 4; ++i) {
                            int ee = e + i;
                            int idx = esrc[ee < e1 ? ee : e1 - 1];
                            m[i] = (ee < e1) ? 1.f : 0.f;
                            d[i] = *(const uint4*)(Xb + (size_t)idx * HD + c * 8);
                        }
#pragma unroll
                        for (int i = 0; i < 4; ++i) {
                            u32 w[4] = {d[i].x, d[i].y, d[i].z, d[i].w};
#pragma unroll
                            for (int j = 0; j < 4; ++j) {
                                s[2 * j]     = fmaf(m[i], bflo(w[j]), s[2 * j]);
                                s[2 * j + 1] = fmaf(m[i], bfhi(w[j]), s[2 * j + 1]);
                            }
                        }
                    }
                }
            }
            uint4 pk;
            pk.x = pk2(s[0] * rcv, s[1] * rcv);
            pk.y = pk2(s[2] * rcv, s[3] * rcv);
            pk.z = pk2(s[4] * rcv, s[5] * rcv);
            pk.w = pk2(s[6] * rcv, s[7] * rcv);
            *(uint4*)(atile + lrow * 128 + ((c ^ (lrow & 15)) << 3)) = pk;
        }
    }
    __syncthreads();

    // ---- phase B: dual-phase MFMA (wave's 16 slots) ----
    f32x4 acc[8];
#pragma unroll
    for (int ct = 0; ct < 8; ++ct) acc[ct] = (f32x4){0.f, 0.f, 0.f, 0.f};

    // phase 0: A = LDS agg tile (swizzled); lrow&15 == lr here
    {
        const u16* wp = wf;
        bf16x8 a[4];
#pragma unroll
        for (int kt = 0; kt < 4; ++kt) {
            int lrow = wid * 16 + lr;
            int ck = (kt * 4 + lg) ^ lr;
            a[kt] = *(const bf16x8*)(atile + lrow * 128 + (ck << 3));
        }
#pragma unroll
        for (int kt = 0; kt < 4; ++kt)
#pragma unroll
            for (int ct = 0; ct < 8; ++ct) {
                bf16x8 w = *(const bf16x8*)(wp + (size_t)(((kt * 8 + ct) << 6) + lane) * 8);
                acc[ct] = __builtin_amdgcn_mfma_f32_16x16x32_bf16(a[kt], w, acc[ct], 0, 0, 0);
            }
    }
    // phase 1: A = self rows (perm'd) from global
    {
        const u16* wp = wf + 16384;
        int slot = m0 + lr; if (slot > Nseg - 1) slot = Nseg - 1;
        int row = perm[pbase + slot];
        bf16x8 a[4];
#pragma unroll
        for (int kt = 0; kt < 4; ++kt)
            a[kt] = *(const bf16x8*)(Xseg + (size_t)row * HD + kt * 32 + lg * 8);
#pragma unroll
        for (int kt = 0; kt < 4; ++kt)
#pragma unroll
            for (int ct = 0; ct < 8; ++ct) {
                bf16x8 w = *(const bf16x8*)(wp + (size_t)(((kt * 8 + ct) << 6) + lane) * 8);
                acc[ct] = __builtin_amdgcn_mfma_f32_16x16x32_bf16(a[kt], w, acc[ct], 0, 0, 0);
            }
    }

    float bv[8];
#pragma unroll
    for (int ct = 0; ct < 8; ++ct) bv[ct] = bias[ct * 16 + lr];

    // ---- phase C: epilogue via per-wave LDS tiles; perm'd 256 B-chunk stores ----
    __syncthreads();
    if (OBF16) {
        u16 (*lds_u)[16][136] = (u16 (*)[16][136])ldsbuf;   // 17408 B total
#pragma unroll
        for (int ct = 0; ct < 8; ++ct)
#pragma unroll
            for (int r = 0; r < 4; ++r) {
                float v = acc[ct][r] + bv[ct];
                if (RELU) v = fmaxf(v, 0.f);
                lds_u[wid][lg * 4 + r][ct * 16 + lr] = f2bf(v);
            }
#pragma unroll
        for (int i = 0; i < 4; ++i) {
            int row16 = i * 4 + lg;
            int colb = lr * 8;
            uint4 pk = *(const uint4*)&lds_u[wid][row16][colb];
            int slot = m0 + row16;
            if (slot < Nseg) {
                int orow = perm[pbase + slot];
                *(uint4*)(outb + (size_t)orow * HD + colb) = pk;
            }
        }
    } else {
        float (*lds_f)[16][68] = (float (*)[16][68])ldsbuf;  // 17408 B total
#pragma unroll
        for (int p = 0; p < 2; ++p) {   // column halves
#pragma unroll
            for (int cq = 0; cq < 4; ++cq) {
                int ct = p * 4 + cq;
#pragma unroll
                for (int r = 0; r < 4; ++r) {
                    float v = acc[ct][r] + bv[ct];
                    if (RELU) v = fmaxf(v, 0.f);
                    lds_f[wid][lg * 4 + r][cq * 16 + lr] = v;
                }
            }
#pragma unroll
            for (int i = 0; i < 4; ++i) {
                int row16 = i * 4 + lg;
                int colb = lr * 4;
                f32x4 v = *(const f32x4*)&lds_f[wid][row16][colb];
                int slot = m0 + row16;
                if (slot < Nseg) {
                    int orow = perm[pbase + slot];
                    __builtin_nontemporal_store(v, (f32x4*)(outf + (size_t)orow * HD + p * 64 + colb));
                }
            }
        }
    }
}

// ---- fused adversarial head: adv = relu(g2 @ A1^T + b1) @ A2^T + b2 ----
__global__ __launch_bounds__(256, 4) void head_kernel(
    const float* __restrict__ g2,     // f32 [NG][128] (out_gene2)
    const u16* __restrict__ wfA1,     // A1 frag buf
    const float* __restrict__ b1,
    const float* __restrict__ A2,     // f32 [8][128]
    const float* __restrict__ b2,
    float* __restrict__ adv)          // f32 [NG][8]
{
    __shared__ __align__(16) u16 lds_h[4][16][136];
    const int tid = threadIdx.x;
    const int lane = tid & 63;
    const int wid = tid >> 6;
    const int m0 = blockIdx.x * 128 + wid * 32;
    const int lr = lane & 15, lg = lane >> 4;

    bf16x8 a2f[4];
#pragma unroll
    for (int kt = 0; kt < 4; ++kt) {
        union { u16 s[8]; bf16x8 v; } u;
        if (lr < 8) {
            const float* p = A2 + (size_t)lr * HD + kt * 32 + lg * 8;
            float4 x = *(const float4*)p;
            float4 y = *(const float4*)(p + 4);
            u.s[0] = f2bf(x.x); u.s[1] = f2bf(x.y); u.s[2] = f2bf(x.z); u.s[3] = f2bf(x.w);
            u.s[4] = f2bf(y.x); u.s[5] = f2bf(y.y); u.s[6] = f2bf(y.z); u.s[7] = f2bf(y.w);
        } else {
#pragma unroll
            for (int i = 0; i < 8; ++i) u.s[i] = 0;
        }
        a2f[kt] = u.v;
    }

    f32x4 acc[2][8];
#pragma unroll
    for (int rt = 0; rt < 2; ++rt)
#pragma unroll
        for (int ct = 0; ct < 8; ++ct) acc[rt][ct] = (f32x4){0.f, 0.f, 0.f, 0.f};

#pragma unroll
    for (int kt = 0; kt < 4; ++kt) {
        bf16x8 a[2];
#pragma unroll
        for (int rt = 0; rt < 2; ++rt) {
            int row = m0 + rt * 16 + lr; if (row > NG - 1) row = NG - 1;
            const float* p = g2 + (size_t)row * HD + kt * 32 + lg * 8;
            float4 x = *(const float4*)p;
            float4 y = *(const float4*)(p + 4);
            union { u16 s[8]; bf16x8 v; } u;
            u.s[0] = f2bf(x.x); u.s[1] = f2bf(x.y); u.s[2] = f2bf(x.z); u.s[3] = f2bf(x.w);
            u.s[4] = f2bf(y.x); u.s[5] = f2bf(y.y); u.s[6] = f2bf(y.z); u.s[7] = f2bf(y.w);
            a[rt] = u.v;
        }
#pragma unroll
        for (int ct = 0; ct < 8; ++ct) {
            bf16x8 w = *(const bf16x8*)(wfA1 + (size_t)(((kt * 8 + ct) << 6) + lane) * 8);
#pragma unroll
            for (int rt = 0; rt < 2; ++rt)
                acc[rt][ct] = __builtin_amdgcn_mfma_f32_16x16x32_bf16(
                    a[rt], w, acc[rt][ct], 0, 0, 0);
        }
    }

    float b1v[8];
#pragma unroll
    for (int ct = 0; ct < 8; ++ct) b1v[ct] = b1[ct * 16 + lr];
    float b2v = (lr < 8) ? b2[lr] : 0.f;

#pragma unroll
    for (int rt = 0; rt < 2; ++rt) {
#pragma unroll
        for (int ct = 0; ct < 8; ++ct)
#pragma unroll
            for (int r = 0; r < 4; ++r) {
                float v = fmaxf(acc[rt][ct][r] + b1v[ct], 0.f);
                lds_h[wid][lg * 4 + r][ct * 16 + lr] = f2bf(v);
            }
        f32x4 av = (f32x4){0.f, 0.f, 0.f, 0.f};
#pragma unroll
        for (int kt = 0; kt < 4; ++kt) {
            bf16x8 h = *(const bf16x8*)&lds_h[wid][lr][kt * 32 + lg * 8];
            av = __builtin_amdgcn_mfma_f32_16x16x32_bf16(h, a2f[kt], av, 0, 0, 0);
        }
        if (lr < 8) {
#pragma unroll
            for (int r = 0; r < 4; ++r) {
                int grow = m0 + rt * 16 + lg * 4 + r;
                if (grow < NG)
                    __builtin_nontemporal_store(av[r] + b2v, &adv[(size_t)grow * 8 + lr]);
            }
        }
    }
}

extern "C" void kernel_launch(void* const* d_in, const int* in_sizes, int n_in,
                              void* d_out, int out_size, void* d_ws, size_t ws_size,
                              hipStream_t stream)
{
    const float* emb_gene = (const float*)d_in[0];
    const float* emb_var  = (const float*)d_in[1];
    const float* Wl1_gv = (const float*)d_in[2];
    const float* bl1_gv = (const float*)d_in[3];
    const float* Wr1_gv = (const float*)d_in[4];
    const float* Wl1_vg = (const float*)d_in[5];
    const float* bl1_vg = (const float*)d_in[6];
    const float* Wr1_vg = (const float*)d_in[7];
    const float* Wl2_gv = (const float*)d_in[8];
    const float* bl2_gv = (const float*)d_in[9];
    const float* Wr2_gv = (const float*)d_in[10];
    const float* Wl2_vg = (const float*)d_in[11];
    const float* bl2_vg = (const float*)d_in[12];
    const float* Wr2_vg = (const float*)d_in[13];
    const float* A1 = (const float*)d_in[14];
    const float* b1 = (const float*)d_in[15];
    const float* A2 = (const float*)d_in[16];
    const float* b2 = (const float*)d_in[17];
    const int* src_gv = (const int*)d_in[18];
    const int* dst_gv = (const int*)d_in[19];
    const int* src_vg = (const int*)d_in[20];
    const int* dst_vg = (const int*)d_in[21];

    // ws layout (bytes) — ws_size ≈ 627 MB (measured r5 poison fill):
    char* ws = (char*)d_ws;
    u16* embb    = (u16*)(ws);                  // bf16 [NALL][128] gene;var  76.8 MB
    u16* zb      = (u16*)(ws + 76800000);       // bf16 [NALL][128] gene;var  76.8 MB
    u16* wfrag   = (u16*)(ws + 153600000);      // 9 x 32 KB fragment bufs
    int* rs      = (int*)(ws + 154000000);      // [NALL+1]
    int* esrc    = (int*)(ws + 155300000);      // [2E]
    int* deg     = (int*)(ws + 159300000);      // [NALL] transient
    int* cur     = (int*)(ws + 160500000);      // [NALL] transient
    int* bsum    = (int*)(ws + 161700000);      // [147]
    int* perm    = (int*)(ws + 161800000);      // [NALL] degree-sorted slots
    int* bcounts = (int*)(ws + 163100000);      // [256][128]
    int* boffs   = (int*)(ws + 163300000);      // [256][128]

    float* out       = (float*)d_out;
    float* out_gene2 = out;                          // [NG][128]
    float* out_var2  = out + (size_t)NG * HD;        // [NV][128]
    float* out_adv   = out + (size_t)(NG + NV) * HD; // [NG][8]

    const int NB = (NALL + 2047) / 2048;   // 147
    const int EB2 = (EALL + 255) / 256;    // 3907
    const int NAB = (NALL + 255) / 256;    // 1172
    const int NVB = (NV + 63) / 64;        // 3125
    const int NGB = (NG + 63) / 64;        // 1563
    const int NGB128 = (NG + 127) / 128;   // 782 (head)
    const int CVB = (int)(((size_t)NALL * HD / 8 + 255) / 256);  // 18750

    // ---- prep: bf16 tables + W fragment bufs + CSR + contention-free sort ----
    hipMemsetAsync(deg, 0, (size_t)NALL * 4, stream);
    cvt_kernel<<<CVB, 256, 0, stream>>>(emb_gene, emb_var, embb);
    wcvt_kernel<<<9, 256, 0, stream>>>(Wl1_gv, Wr1_gv, Wl1_vg, Wr1_vg,
                                       Wl2_gv, Wr2_gv, Wl2_vg, Wr2_vg, A1, wfrag);
    hist2_kernel<<<EB2, 256, 0, stream>>>(dst_gv, dst_vg, deg);
    scan1_kernel<<<NB, 256, 0, stream>>>(deg, rs, bsum, NALL);
    scan2_kernel<<<1, 64, 0, stream>>>(bsum, NB);
    scan3_kernel<<<NAB, 256, 0, stream>>>(rs, cur, bsum, NALL);
    escatter2_kernel<<<EB2, 256, 0, stream>>>(src_gv, dst_gv, src_vg, dst_vg, cur, esrc);
    sortA_kernel<<<NSB, 256, 0, stream>>>(rs, bcounts);
    sortB_kernel<<<1, 128, 0, stream>>>(bcounts, boffs);
    sortC_kernel<<<NSB, 256, 0, stream>>>(rs, boffs, perm);

    // ---- layer 1: fused gather-mean + MFMA dual-GEMM -> zb (bf16, relu) ----
    fused_sage_kernel<1, 1><<<NVB + NGB, 256, 0, stream>>>(embb, rs, esrc, perm,
        wfrag + 0 * 16384, wfrag + 2 * 16384, bl1_gv, bl1_vg,
        nullptr, nullptr,
        zb + (size_t)NG * HD, zb,
        NVB);

    // ---- layer 2: fused gather-mean + MFMA dual-GEMM -> d_out (f32, NT stores) ----
    fused_sage_kernel<0, 0><<<NVB + NGB, 256, 0, stream>>>(zb, rs, esrc, perm,
        wfrag + 4 * 16384, wfrag + 6 * 16384, bl2_gv, bl2_vg,
        out_var2, out_gene2,
        nullptr, nullptr,
        NVB);

    // ---- fused adversarial head ----
    head_kernel<<<NGB128, 256, 0, stream>>>(out_gene2, wfrag + 8 * 16384, b1, A2, b2, out_adv);
}

// Round 18
// 414.006 us; speedup vs baseline: 5.7239x; 1.1956x over previous
//
#include <hip/hip_runtime.h>
#include <hip/hip_bf16.h>

typedef unsigned short u16;
typedef unsigned int u32;
typedef __attribute__((ext_vector_type(8))) short bf16x8;
typedef __attribute__((ext_vector_type(4))) float f32x4;

#define NG 100000
#define NV 200000
#define NE 500000
#define HD 128
#define NALL (NG + NV)          // combined node count: gene rows 0.., var rows NG..
#define EALL (2 * NE)

__device__ __forceinline__ float bflo(u32 w) { return __uint_as_float(w << 16); }
__device__ __forceinline__ float bfhi(u32 w) { return __uint_as_float(w & 0xffff0000u); }
__device__ __forceinline__ u16 f2bf(float f) {
    __hip_bfloat16 h = __float2bfloat16(f);
    u16 u; __builtin_memcpy(&u, &h, 2); return u;
}
__device__ __forceinline__ u32 pk2(float a, float b) {
    return (u32)f2bf(a) | ((u32)f2bf(b) << 16);
}

// ---- convert both f32 tables into one combined bf16 table [gene; var] ----
// (cached stores: embb is re-read by layer-1 gathers -> want L3 residency)
__global__ __launch_bounds__(256) void cvt_kernel(const float* __restrict__ g,
                                                  const float* __restrict__ v,
                                                  u16* __restrict__ out) {
    size_t slot = (size_t)blockIdx.x * 256 + threadIdx.x;   // 8 elems per slot
    size_t off = slot * 8;
    if (off >= (size_t)NALL * HD) return;
    const float* p = (off < (size_t)NG * HD) ? (g + off) : (v + (off - (size_t)NG * HD));
    float4 a = *(const float4*)p;
    float4 b = *(const float4*)(p + 4);
    uint4 pk;
    pk.x = pk2(a.x, a.y); pk.y = pk2(a.z, a.w);
    pk.z = pk2(b.x, b.y); pk.w = pk2(b.z, b.w);
    *(uint4*)(out + off) = pk;
}

// ---- convert 9 weight matrices f32 [128][128] -> fragment-ordered bf16 ----
// buf[f=kt*8+ct][lane][8]: row = ct*16 + (lane&15), k = kt*32 + (lane>>4)*8 + j.
__global__ __launch_bounds__(256) void wcvt_kernel(
    const float* w0, const float* w1, const float* w2, const float* w3,
    const float* w4, const float* w5, const float* w6, const float* w7,
    const float* w8, u16* __restrict__ out)
{
    const float* Ws[9] = {w0, w1, w2, w3, w4, w5, w6, w7, w8};
    const float* W = Ws[blockIdx.x];
    u16* o = out + (size_t)blockIdx.x * 16384;
    int tid = threadIdx.x;
#pragma unroll
    for (int it = 0; it < 8; ++it) {
        int slot = it * 256 + tid;       // 0..2047
        int f = slot >> 6, l = slot & 63;
        int kt = f >> 3, ct = f & 7;
        int row = ct * 16 + (l & 15);
        int kof = kt * 32 + (l >> 4) * 8;
        const float* wp = W + (size_t)row * HD + kof;
        float4 x = *(const float4*)wp;
        float4 y = *(const float4*)(wp + 4);
        uint4 pk;
        pk.x = pk2(x.x, x.y); pk.y = pk2(x.z, x.w);
        pk.z = pk2(y.x, y.y); pk.w = pk2(y.z, y.w);
        *(uint4*)(o + (size_t)slot * 8) = pk;
    }
}

// ---- combined histogram over both edge lists: dst var -> [0,NV), gene -> NV+ ----
__global__ __launch_bounds__(256) void hist2_kernel(const int* __restrict__ dst_gv,
                                                    const int* __restrict__ dst_vg,
                                                    int* __restrict__ deg) {
    int t = blockIdx.x * 256 + threadIdx.x;
    if (t < NE)            atomicAdd(&deg[dst_gv[t]], 1);
    else if (t < EALL)     atomicAdd(&deg[NV + dst_vg[t - NE]], 1);
}

// ---- scan stage 1: per-block (2048) exclusive scan + block sums ----
__global__ __launch_bounds__(256) void scan1_kernel(const int* __restrict__ deg,
                                                    int* __restrict__ excl,
                                                    int* __restrict__ bsum, int N) {
    __shared__ int lds[256];
    int tid = threadIdx.x;
    int base = blockIdx.x * 2048 + tid * 8;
    int v[8]; int s = 0;
#pragma unroll
    for (int i = 0; i < 8; ++i) { v[i] = (base + i < N) ? deg[base + i] : 0; s += v[i]; }
    lds[tid] = s;
    __syncthreads();
    for (int off = 1; off < 256; off <<= 1) {
        int x = (tid >= off) ? lds[tid - off] : 0;
        __syncthreads();
        lds[tid] += x;
        __syncthreads();
    }
    int run = lds[tid] - s;
#pragma unroll
    for (int i = 0; i < 8; ++i) {
        if (base + i < N) excl[base + i] = run;
        run += v[i];
    }
    if (tid == 255) bsum[blockIdx.x] = lds[255];
}

__global__ void scan2_kernel(int* __restrict__ bsum, int nb) {
    if (threadIdx.x == 0 && blockIdx.x == 0) {
        int run = 0;
        for (int i = 0; i < nb; ++i) { int t = bsum[i]; bsum[i] = run; run += t; }
    }
}

__global__ __launch_bounds__(256) void scan3_kernel(int* __restrict__ rs,
                                                    int* __restrict__ cur,
                                                    const int* __restrict__ bsum, int N) {
    int i = blockIdx.x * 256 + threadIdx.x;
    if (i < N) {
        int v = rs[i] + bsum[i >> 11];
        rs[i] = v;
        cur[i] = v;
    }
    if (i == 0) rs[N] = EALL;
}

// ---- combined edge scatter; esrc stored pre-offset into the combined table ----
__global__ __launch_bounds__(256) void escatter2_kernel(const int* __restrict__ src_gv,
                                                        const int* __restrict__ dst_gv,
                                                        const int* __restrict__ src_vg,
                                                        const int* __restrict__ dst_vg,
                                                        int* __restrict__ cur,
                                                        int* __restrict__ esrc) {
    int t = blockIdx.x * 256 + threadIdx.x;
    if (t < NE) {
        int p = atomicAdd(&cur[dst_gv[t]], 1);
        esrc[p] = src_gv[t];
    } else if (t < EALL) {
        int e = t - NE;
        int p = atomicAdd(&cur[NV + dst_vg[e]], 1);
        esrc[p] = NG + src_vg[e];
    }
}

// ---- fused aggregate + dual-segment MFMA SAGE linear, 64-row blocks ----
// Final form (r15, best measured 415 us). Evidence bracket (r10-r17):
//  - occupancy >~55% is register-gated: bound 8/6 with 2-row gather spilled
//    (true demand ~112 regs incl. 32 unified-file acc); single-row fits cap 85.
//  - gather ILP >4-deep is register-gated (r11 neutral at cap 102).
//  - NT stores on f32 out: +3% (write-path), FETCH unchanged (r15).
//  - degree-sorting: divergence saved < locality lost (r17, FETCH +18 MB).
// Remaining cost is intrinsic: ~1M random 256 B L3 gathers/layer @ ~200 cyc.
// LDS 17408 B (16 KB atile U 17 KB epilogue); __launch_bounds__(256,6).
// Swizzle: chunk (row,c) at row*256B + ((c ^ (row&15)))*16B.
// Fragment map (m89-verified): A row=lane&15, k=8*(lane>>4)+j; B col=lane&15;
// D col=lane&15, row=4*(lane>>4)+reg.
template <int RELU, int OBF16>
__global__ __launch_bounds__(256, 6) void fused_sage_kernel(
    const u16* __restrict__ Xb,     // combined [gene; var] bf16 table
    const int* __restrict__ rs,     // CSR row starts (var 0.., gene NV..)
    const int* __restrict__ esrc,   // edge sources (combined X row index)
    const u16* __restrict__ wf_v, const u16* __restrict__ wf_g,
    const float* __restrict__ b_v, const float* __restrict__ b_g,
    float* __restrict__ outf_v, float* __restrict__ outf_g,
    u16* __restrict__ outb_v, u16* __restrict__ outb_g,
    int nvb)
{
    __shared__ __align__(16) char ldsbuf[17408];   // atile 16384 | epilogue 17408 (union)
    u16* atile = (u16*)ldsbuf;                     // [64][128] swizzled

    const bool isVar = (int)blockIdx.x < nvb;
    const int bseg = isVar ? blockIdx.x : blockIdx.x - nvb;
    const int Nseg = isVar ? NV : NG;
    const int gseg = isVar ? 0 : NV;                      // CSR row-space offset
    const u16* Xseg = Xb + (size_t)(isVar ? NG : 0) * HD; // self rows
    const u16* wf = isVar ? wf_v : wf_g;
    const float* bias = isVar ? b_v : b_g;
    float* outf = isVar ? outf_v : outf_g;
    u16* outb = isVar ? outb_v : outb_g;

    const int tid = threadIdx.x;
    const int lane = tid & 63;
    const int wid = tid >> 6;
    const int m0 = bseg * 64 + wid * 16;
    const int lr = lane & 15, lg = lane >> 4;

    // ---- phase A: gather-mean 64 rows into swizzled LDS tile ----
    {
        const int c = tid & 15;
#pragma unroll 1
        for (int it = 0; it < 4; ++it) {
            int lrow = it * 16 + (tid >> 4);
            int srow = bseg * 64 + lrow;
            float s[8] = {0.f, 0.f, 0.f, 0.f, 0.f, 0.f, 0.f, 0.f};
            float rcv = 0.f;
            if (srow < Nseg) {
                int e0 = rs[gseg + srow], e1 = rs[gseg + srow + 1];
                if (e1 > e0) {
                    rcv = 1.f / (float)(e1 - e0);
                    for (int e = e0; e < e1; e += 4) {   // 4 loads in flight, predicated
                        uint4 d[4];
                        float m[4];
#pragma unroll
                        for (int i = 0; i < 4; ++i) {
                            int ee = e + i;
                            int idx = esrc[ee < e1 ? ee : e1 - 1];
                            m[i] = (ee < e1) ? 1.f : 0.f;
                            d[i] = *(const uint4*)(Xb + (size_t)idx * HD + c * 8);
                        }
#pragma unroll
                        for (int i = 0; i < 4; ++i) {
                            u32 w[4] = {d[i].x, d[i].y, d[i].z, d[i].w};
#pragma unroll
                            for (int j = 0; j < 4; ++j) {
                                s[2 * j]     = fmaf(m[i], bflo(w[j]), s[2 * j]);
                                s[2 * j + 1] = fmaf(m[i], bfhi(w[j]), s[2 * j + 1]);
                            }
                        }
                    }
                }
            }
            uint4 pk;
            pk.x = pk2(s[0] * rcv, s[1] * rcv);
            pk.y = pk2(s[2] * rcv, s[3] * rcv);
            pk.z = pk2(s[4] * rcv, s[5] * rcv);
            pk.w = pk2(s[6] * rcv, s[7] * rcv);
            *(uint4*)(atile + lrow * 128 + ((c ^ (lrow & 15)) << 3)) = pk;
        }
    }
    __syncthreads();

    // ---- phase B: dual-phase MFMA (wave's 16 rows) ----
    f32x4 acc[8];
#pragma unroll
    for (int ct = 0; ct < 8; ++ct) acc[ct] = (f32x4){0.f, 0.f, 0.f, 0.f};

    // phase 0: A = LDS agg tile (swizzled); lrow&15 == lr here
    {
        const u16* wp = wf;
        bf16x8 a[4];
#pragma unroll
        for (int kt = 0; kt < 4; ++kt) {
            int lrow = wid * 16 + lr;
            int ck = (kt * 4 + lg) ^ lr;
            a[kt] = *(const bf16x8*)(atile + lrow * 128 + (ck << 3));
        }
#pragma unroll
        for (int kt = 0; kt < 4; ++kt)
#pragma unroll
            for (int ct = 0; ct < 8; ++ct) {
                bf16x8 w = *(const bf16x8*)(wp + (size_t)(((kt * 8 + ct) << 6) + lane) * 8);
                acc[ct] = __builtin_amdgcn_mfma_f32_16x16x32_bf16(a[kt], w, acc[ct], 0, 0, 0);
            }
    }
    // phase 1: A = self rows from global
    {
        const u16* wp = wf + 16384;
        bf16x8 a[4];
#pragma unroll
        for (int kt = 0; kt < 4; ++kt) {
            int row = m0 + lr; if (row > Nseg - 1) row = Nseg - 1;
            a[kt] = *(const bf16x8*)(Xseg + (size_t)row * HD + kt * 32 + lg * 8);
        }
#pragma unroll
        for (int kt = 0; kt < 4; ++kt)
#pragma unroll
            for (int ct = 0; ct < 8; ++ct) {
                bf16x8 w = *(const bf16x8*)(wp + (size_t)(((kt * 8 + ct) << 6) + lane) * 8);
                acc[ct] = __builtin_amdgcn_mfma_f32_16x16x32_bf16(a[kt], w, acc[ct], 0, 0, 0);
            }
    }

    float bv[8];
#pragma unroll
    for (int ct = 0; ct < 8; ++ct) bv[ct] = bias[ct * 16 + lr];

    // ---- phase C: epilogue via per-wave LDS tiles (alias atile -> one barrier) ----
    __syncthreads();
    if (OBF16) {
        u16 (*lds_u)[16][136] = (u16 (*)[16][136])ldsbuf;   // 17408 B total
#pragma unroll
        for (int ct = 0; ct < 8; ++ct)
#pragma unroll
            for (int r = 0; r < 4; ++r) {
                float v = acc[ct][r] + bv[ct];
                if (RELU) v = fmaxf(v, 0.f);
                lds_u[wid][lg * 4 + r][ct * 16 + lr] = f2bf(v);
            }
#pragma unroll
        for (int i = 0; i < 4; ++i) {
            int row16 = i * 4 + lg;
            int colb = lr * 8;
            uint4 pk = *(const uint4*)&lds_u[wid][row16][colb];
            int grow = m0 + row16;
            if (grow < Nseg) *(uint4*)(outb + (size_t)grow * HD + colb) = pk;
        }
    } else {
        float (*lds_f)[16][68] = (float (*)[16][68])ldsbuf;  // 17408 B total
#pragma unroll
        for (int p = 0; p < 2; ++p) {   // column halves
#pragma unroll
            for (int cq = 0; cq < 4; ++cq) {
                int ct = p * 4 + cq;
#pragma unroll
                for (int r = 0; r < 4; ++r) {
                    float v = acc[ct][r] + bv[ct];
                    if (RELU) v = fmaxf(v, 0.f);
                    lds_f[wid][lg * 4 + r][cq * 16 + lr] = v;
                }
            }
#pragma unroll
            for (int i = 0; i < 4; ++i) {
                int row16 = i * 4 + lg;
                int colb = lr * 4;
                f32x4 v = *(const f32x4*)&lds_f[wid][row16][colb];
                int grow = m0 + row16;
                if (grow < Nseg)  // non-temporal: write-once stream, keep L3 for gathers
                    __builtin_nontemporal_store(v, (f32x4*)(outf + (size_t)grow * HD + p * 64 + colb));
            }
        }
    }
}

// ---- fused adversarial head: adv = relu(g2 @ A1^T + b1) @ A2^T + b2 ----
// All LDS is per-wave -> no barriers needed.
__global__ __launch_bounds__(256, 4) void head_kernel(
    const float* __restrict__ g2,     // f32 [NG][128] (out_gene2)
    const u16* __restrict__ wfA1,     // A1 frag buf
    const float* __restrict__ b1,
    const float* __restrict__ A2,     // f32 [8][128]
    const float* __restrict__ b2,
    float* __restrict__ adv)          // f32 [NG][8]
{
    __shared__ __align__(16) u16 lds_h[4][16][136];
    const int tid = threadIdx.x;
    const int lane = tid & 63;
    const int wid = tid >> 6;
    const int m0 = blockIdx.x * 128 + wid * 32;
    const int lr = lane & 15, lg = lane >> 4;

    bf16x8 a2f[4];
#pragma unroll
    for (int kt = 0; kt < 4; ++kt) {
        union { u16 s[8]; bf16x8 v; } u;
        if (lr < 8) {
            const float* p = A2 + (size_t)lr * HD + kt * 32 + lg * 8;
            float4 x = *(const float4*)p;
            float4 y = *(const float4*)(p + 4);
            u.s[0] = f2bf(x.x); u.s[1] = f2bf(x.y); u.s[2] = f2bf(x.z); u.s[3] = f2bf(x.w);
            u.s[4] = f2bf(y.x); u.s[5] = f2bf(y.y); u.s[6] = f2bf(y.z); u.s[7] = f2bf(y.w);
        } else {
#pragma unroll
            for (int i = 0; i < 8; ++i) u.s[i] = 0;
        }
        a2f[kt] = u.v;
    }

    f32x4 acc[2][8];
#pragma unroll
    for (int rt = 0; rt < 2; ++rt)
#pragma unroll
        for (int ct = 0; ct < 8; ++ct) acc[rt][ct] = (f32x4){0.f, 0.f, 0.f, 0.f};

#pragma unroll
    for (int kt = 0; kt < 4; ++kt) {
        bf16x8 a[2];
#pragma unroll
        for (int rt = 0; rt < 2; ++rt) {
            int row = m0 + rt * 16 + lr; if (row > NG - 1) row = NG - 1;
            const float* p = g2 + (size_t)row * HD + kt * 32 + lg * 8;
            float4 x = *(const float4*)p;
            float4 y = *(const float4*)(p + 4);
            union { u16 s[8]; bf16x8 v; } u;
            u.s[0] = f2bf(x.x); u.s[1] = f2bf(x.y); u.s[2] = f2bf(x.z); u.s[3] = f2bf(x.w);
            u.s[4] = f2bf(y.x); u.s[5] = f2bf(y.y); u.s[6] = f2bf(y.z); u.s[7] = f2bf(y.w);
            a[rt] = u.v;
        }
#pragma unroll
        for (int ct = 0; ct < 8; ++ct) {
            bf16x8 w = *(const bf16x8*)(wfA1 + (size_t)(((kt * 8 + ct) << 6) + lane) * 8);
#pragma unroll
            for (int rt = 0; rt < 2; ++rt)
                acc[rt][ct] = __builtin_amdgcn_mfma_f32_16x16x32_bf16(
                    a[rt], w, acc[rt][ct], 0, 0, 0);
        }
    }

    float b1v[8];
#pragma unroll
    for (int ct = 0; ct < 8; ++ct) b1v[ct] = b1[ct * 16 + lr];
    float b2v = (lr < 8) ? b2[lr] : 0.f;

#pragma unroll
    for (int rt = 0; rt < 2; ++rt) {
#pragma unroll
        for (int ct = 0; ct < 8; ++ct)
#pragma unroll
            for (int r = 0; r < 4; ++r) {
                float v = fmaxf(acc[rt][ct][r] + b1v[ct], 0.f);
                lds_h[wid][lg * 4 + r][ct * 16 + lr] = f2bf(v);
            }
        f32x4 av = (f32x4){0.f, 0.f, 0.f, 0.f};
#pragma unroll
        for (int kt = 0; kt < 4; ++kt) {
            bf16x8 h = *(const bf16x8*)&lds_h[wid][lr][kt * 32 + lg * 8];
            av = __builtin_amdgcn_mfma_f32_16x16x32_bf16(h, a2f[kt], av, 0, 0, 0);
        }
        if (lr < 8) {
#pragma unroll
            for (int r = 0; r < 4; ++r) {
                int grow = m0 + rt * 16 + lg * 4 + r;
                if (grow < NG)
                    __builtin_nontemporal_store(av[r] + b2v, &adv[(size_t)grow * 8 + lr]);
            }
        }
    }
}

extern "C" void kernel_launch(void* const* d_in, const int* in_sizes, int n_in,
                              void* d_out, int out_size, void* d_ws, size_t ws_size,
                              hipStream_t stream)
{
    const float* emb_gene = (const float*)d_in[0];
    const float* emb_var  = (const float*)d_in[1];
    const float* Wl1_gv = (const float*)d_in[2];
    const float* bl1_gv = (const float*)d_in[3];
    const float* Wr1_gv = (const float*)d_in[4];
    const float* Wl1_vg = (const float*)d_in[5];
    const float* bl1_vg = (const float*)d_in[6];
    const float* Wr1_vg = (const float*)d_in[7];
    const float* Wl2_gv = (const float*)d_in[8];
    const float* bl2_gv = (const float*)d_in[9];
    const float* Wr2_gv = (const float*)d_in[10];
    const float* Wl2_vg = (const float*)d_in[11];
    const float* bl2_vg = (const float*)d_in[12];
    const float* Wr2_vg = (const float*)d_in[13];
    const float* A1 = (const float*)d_in[14];
    const float* b1 = (const float*)d_in[15];
    const float* A2 = (const float*)d_in[16];
    const float* b2 = (const float*)d_in[17];
    const int* src_gv = (const int*)d_in[18];
    const int* dst_gv = (const int*)d_in[19];
    const int* src_vg = (const int*)d_in[20];
    const int* dst_vg = (const int*)d_in[21];

    // ws layout (bytes) — ws_size ≈ 627 MB (measured r5 poison fill):
    char* ws = (char*)d_ws;
    u16* embb  = (u16*)(ws);                  // bf16 [NALL][128] gene;var  76.8 MB
    u16* zb    = (u16*)(ws + 76800000);       // bf16 [NALL][128] gene;var  76.8 MB
    u16* wfrag = (u16*)(ws + 153600000);      // 9 x 32 KB fragment bufs
    int* rs    = (int*)(ws + 154000000);      // [NALL+1]
    int* esrc  = (int*)(ws + 155300000);      // [2E]
    int* deg   = (int*)(ws + 159300000);      // [NALL] transient
    int* cur   = (int*)(ws + 160500000);      // [NALL] transient
    int* bsum  = (int*)(ws + 161700000);      // [147]

    float* out       = (float*)d_out;
    float* out_gene2 = out;                          // [NG][128]
    float* out_var2  = out + (size_t)NG * HD;        // [NV][128]
    float* out_adv   = out + (size_t)(NG + NV) * HD; // [NG][8]

    const int NB = (NALL + 2047) / 2048;   // 147
    const int EB2 = (EALL + 255) / 256;    // 3907
    const int NVB = (NV + 63) / 64;        // 3125
    const int NGB = (NG + 63) / 64;        // 1563
    const int NGB128 = (NG + 127) / 128;   // 782 (head)
    const int CVB = (int)(((size_t)NALL * HD / 8 + 255) / 256);  // 18750

    // ---- prep: bf16 tables + W fragment bufs + CSR over combined graph ----
    hipMemsetAsync(deg, 0, (size_t)NALL * 4, stream);
    cvt_kernel<<<CVB, 256, 0, stream>>>(emb_gene, emb_var, embb);
    wcvt_kernel<<<9, 256, 0, stream>>>(Wl1_gv, Wr1_gv, Wl1_vg, Wr1_vg,
                                       Wl2_gv, Wr2_gv, Wl2_vg, Wr2_vg, A1, wfrag);
    hist2_kernel<<<EB2, 256, 0, stream>>>(dst_gv, dst_vg, deg);
    scan1_kernel<<<NB, 256, 0, stream>>>(deg, rs, bsum, NALL);
    scan2_kernel<<<1, 64, 0, stream>>>(bsum, NB);
    scan3_kernel<<<(NALL + 255) / 256, 256, 0, stream>>>(rs, cur, bsum, NALL);
    escatter2_kernel<<<EB2, 256, 0, stream>>>(src_gv, dst_gv, src_vg, dst_vg, cur, esrc);

    // ---- layer 1: fused gather-mean + MFMA dual-GEMM -> zb (bf16, relu) ----
    fused_sage_kernel<1, 1><<<NVB + NGB, 256, 0, stream>>>(embb, rs, esrc,
        wfrag + 0 * 16384, wfrag + 2 * 16384, bl1_gv, bl1_vg,
        nullptr, nullptr,
        zb + (size_t)NG * HD, zb,
        NVB);

    // ---- layer 2: fused gather-mean + MFMA dual-GEMM -> d_out (f32, NT stores) ----
    fused_sage_kernel<0, 0><<<NVB + NGB, 256, 0, stream>>>(zb, rs, esrc,
        wfrag + 4 * 16384, wfrag + 6 * 16384, bl2_gv, bl2_vg,
        out_var2, out_gene2,
        nullptr, nullptr,
        NVB);

    // ---- fused adversarial head ----
    head_kernel<<<NGB128, 256, 0, stream>>>(out_gene2, wfrag + 8 * 16384, b1, A2, b2, out_adv);
}